// Round 2
// baseline (621.414 us; speedup 1.0000x reference)
//
#include <hip/hip_runtime.h>
#include <cstddef>

namespace {
constexpr int Z    = 4;
constexpr int N    = 256;
constexpr int CIN  = 32;
constexpr int COUT = 32;
constexpr int HID  = 64;
constexpr int OC   = COUT * CIN;  // 1024
}

// ---------------------------------------------------------------------------
// One block per (z, b), fully fused:
//   M[i][h]  = sum_j W2[h][i*32+j] * f[z,b,j]          (LDS, 8 KB)
//   bf[i]    = sum_j b2[i*32+j]   * f[z,b,j]
//   H[a][h]  = relu((g[z,b]-g[z,a]) @ W1 + b1)          (registers, per-thread)
//   out[z,a,b,i] = sum_h H[a][h]*M[i][h] + bf[i]
// Thread tile: 8 a x 4 i, H built in registers per k-chunk (no 64 KB H buffer).
// blockIdx swizzle: XCD k (blk%8) owns b in [32k,32k+32) so neighboring-b
// output segments (adjacent 128 B in memory) stay in ONE XCD's L2.
// ---------------------------------------------------------------------------
__global__ __launch_bounds__(256, 4) void fused_pair(
    const float* __restrict__ features,
    const float* __restrict__ geometry,
    const float* __restrict__ W1,
    const float* __restrict__ b1,
    const float* __restrict__ W2,
    const float* __restrict__ b2,
    float* __restrict__ out)
{
    __shared__ __align__(16) float Ml[COUT * HID];   // 2048 f = 8 KB, M[i][h]
    __shared__ __align__(16) float stage[128 * 36];  // 4608 f = 18 KB
    __shared__ __align__(16) float geo[N * 3];       // 768 f = 3 KB
    __shared__ __align__(16) float w1l[4 * HID];     // W1 rows x,y,z + b1 = 1 KB
    __shared__ __align__(16) float fl[CIN];
    __shared__ float bfl[COUT];

    const int blk = blockIdx.x;          // 1024
    const int xcd = blk & 7;
    const int idx = blk >> 3;            // 0..127
    const int b   = (xcd << 5) | (idx & 31);
    const int z   = idx >> 5;            // 0..3
    const int t   = threadIdx.x;

    // ---- cooperative loads ----
    if (t < 192)
        reinterpret_cast<float4*>(geo)[t] =
            reinterpret_cast<const float4*>(geometry + (size_t)z * N * 3)[t];
    if (t < HID) {
        w1l[t]            = W1[t];
        w1l[HID + t]      = W1[HID + t];
        w1l[2 * HID + t]  = W1[2 * HID + t];
        w1l[3 * HID + t]  = b1[t];
    }
    if (t < CIN) fl[t] = features[((size_t)z * N + b) * CIN + t];
    __syncthreads();

    // ---- M phase: 2048 (i,hh) dots, 8/thread; hh fast across lanes so the
    //      Ml[i*64+hh] writes are conflict-free; W2 lines reused 8x via L1.
    {
        float4 f4r[8];
#pragma unroll
        for (int q = 0; q < 8; ++q) f4r[q] = *reinterpret_cast<const float4*>(&fl[q * 4]);
        const int hh = t & 63;
        const int i0 = t >> 6;           // 0..3
#pragma unroll
        for (int p = 0; p < 8; ++p) {
            const int i = i0 + 4 * p;    // 0..31
            const float4* w2r = reinterpret_cast<const float4*>(
                W2 + (size_t)hh * OC + i * CIN);
            float v = 0.f;
#pragma unroll
            for (int q = 0; q < 8; ++q) {
                const float4 w = w2r[q];
                const float4 f = f4r[q];
                v += w.x * f.x + w.y * f.y + w.z * f.z + w.w * f.w;
            }
            Ml[i * HID + hh] = v;
        }
        if (t < COUT) {
            const float4* b2r = reinterpret_cast<const float4*>(b2 + t * CIN);
            float v = 0.f;
#pragma unroll
            for (int q = 0; q < 8; ++q) {
                const float4 bb = b2r[q];
                const float4 f  = f4r[q];
                v += bb.x * f.x + bb.y * f.y + bb.z * f.z + bb.w * f.w;
            }
            bfl[t] = v;
        }
    }

    // per-thread geometry diffs for 8 a-rows (registers)
    const int a_thr = t & 31;
    const int i_thr = t >> 5;            // 0..7
    __syncthreads();

    const float gbx = geo[b * 3 + 0], gby = geo[b * 3 + 1], gbz = geo[b * 3 + 2];
    float dx[8], dy[8], dz[8];
#pragma unroll
    for (int u = 0; u < 8; ++u) {
        const int a = a_thr + 32 * u;
        dx[u] = gbx - geo[a * 3 + 0];
        dy[u] = gby - geo[a * 3 + 1];
        dz[u] = gbz - geo[a * 3 + 2];
    }

    float acc[8][4];
#pragma unroll
    for (int u = 0; u < 8; ++u)
#pragma unroll
        for (int v = 0; v < 4; ++v) acc[u][v] = bfl[i_thr * 4 + v];

    // ---- main loop: per k-chunk build H in registers, FMA against M ----
#pragma unroll
    for (int k4 = 0; k4 < 16; ++k4) {
        const float4 w1x = *reinterpret_cast<const float4*>(&w1l[k4 * 4]);
        const float4 w1y = *reinterpret_cast<const float4*>(&w1l[HID + k4 * 4]);
        const float4 w1z = *reinterpret_cast<const float4*>(&w1l[2 * HID + k4 * 4]);
        const float4 b1v = *reinterpret_cast<const float4*>(&w1l[3 * HID + k4 * 4]);
        float4 m[4];
#pragma unroll
        for (int v = 0; v < 4; ++v)
            m[v] = *reinterpret_cast<const float4*>(&Ml[(i_thr * 4 + v) * HID + k4 * 4]);
#pragma unroll
        for (int u = 0; u < 8; ++u) {
            float4 h;
            h.x = fmaxf(fmaf(dx[u], w1x.x, fmaf(dy[u], w1y.x, fmaf(dz[u], w1z.x, b1v.x))), 0.f);
            h.y = fmaxf(fmaf(dx[u], w1x.y, fmaf(dy[u], w1y.y, fmaf(dz[u], w1z.y, b1v.y))), 0.f);
            h.z = fmaxf(fmaf(dx[u], w1x.z, fmaf(dy[u], w1y.z, fmaf(dz[u], w1z.z, b1v.z))), 0.f);
            h.w = fmaxf(fmaf(dx[u], w1x.w, fmaf(dy[u], w1y.w, fmaf(dz[u], w1z.w, b1v.w))), 0.f);
#pragma unroll
            for (int v = 0; v < 4; ++v)
                acc[u][v] += h.x * m[v].x + h.y * m[v].y + h.z * m[v].z + h.w * m[v].w;
        }
    }

    // ---- epilogue: transpose through LDS in two 128-a halves, coalesced stores
    const size_t out_zb = ((size_t)z * N) * N + b;   // (z*N + a)*N + b with a added later
#pragma unroll
    for (int half = 0; half < 2; ++half) {
        __syncthreads();   // protect stage reuse (and first use after GEMM reads)
#pragma unroll
        for (int u = 0; u < 4; ++u) {
            const int uu = half * 4 + u;
            float4 o;
            o.x = acc[uu][0]; o.y = acc[uu][1]; o.z = acc[uu][2]; o.w = acc[uu][3];
            *reinterpret_cast<float4*>(&stage[(a_thr + 32 * u) * 36 + i_thr * 4]) = o;
        }
        __syncthreads();
#pragma unroll
        for (int r = 0; r < 4; ++r) {
            const int c     = r * 256 + t;      // 0..1023
            const int a_loc = c >> 3;           // 0..127
            const int i4    = c & 7;
            const int a     = half * 128 + a_loc;
            const float4 val = *reinterpret_cast<const float4*>(&stage[a_loc * 36 + i4 * 4]);
            *reinterpret_cast<float4*>(
                &out[(out_zb + (size_t)a * N) * COUT + i4 * 4]) = val;
        }
    }
}

extern "C" void kernel_launch(void* const* d_in, const int* in_sizes, int n_in,
                              void* d_out, int out_size, void* d_ws, size_t ws_size,
                              hipStream_t stream) {
    const float* features = (const float*)d_in[0];
    const float* geometry = (const float*)d_in[1];
    const float* W1 = (const float*)d_in[2];
    const float* b1 = (const float*)d_in[3];
    const float* W2 = (const float*)d_in[4];
    const float* b2 = (const float*)d_in[5];
    float* out = (float*)d_out;

    fused_pair<<<Z * N, 256, 0, stream>>>(features, geometry, W1, b1, W2, b2, out);
}

// Round 3
// 363.831 us; speedup vs baseline: 1.7080x; 1.7080x over previous
//
#include <hip/hip_runtime.h>
#include <cstddef>

namespace {
constexpr int Z    = 4;
constexpr int N    = 256;
constexpr int CIN  = 32;
constexpr int COUT = 32;
constexpr int HID  = 64;
constexpr int OC   = COUT * CIN;  // 1024
}

// ---------------------------------------------------------------------------
// One block per (z, b), fully fused:
//   M[i][h]  = sum_j W2[h][i*32+j] * f[z,b,j]          (LDS, 8 KB)
//   bf[i]    = sum_j b2[i*32+j]   * f[z,b,j]
//   H[a][h]  = relu((g[z,b]-g[z,a]) @ W1 + b1)          (registers, per-thread)
//   out[z,a,b,i] = sum_h H[a][h]*M[i][h] + bf[i]
// Thread tile: 8 a x 4 i, H built in registers per k-chunk.
// __launch_bounds__(256, 2): R2's (256,4) clamped to 64 VGPRs -> scratch
// spill (1.8 GB HBM, VALUBusy 5%). Live set needs ~105 VGPRs; (256,2) is the
// R1-verified no-spill configuration. LDS (31 KB) still allows 4-5 blocks/CU.
// blockIdx swizzle: XCD k (blk%8) owns b in [32k,32k+32) so neighboring-b
// output segments (adjacent 128 B in memory) stay in ONE XCD's L2.
// ---------------------------------------------------------------------------
__global__ __launch_bounds__(256, 2) void fused_pair(
    const float* __restrict__ features,
    const float* __restrict__ geometry,
    const float* __restrict__ W1,
    const float* __restrict__ b1,
    const float* __restrict__ W2,
    const float* __restrict__ b2,
    float* __restrict__ out)
{
    __shared__ __align__(16) float Ml[COUT * HID];   // 2048 f = 8 KB, M[i][h]
    __shared__ __align__(16) float stage[128 * 36];  // 4608 f = 18 KB
    __shared__ __align__(16) float geo[N * 3];       // 768 f = 3 KB
    __shared__ __align__(16) float w1l[4 * HID];     // W1 rows x,y,z + b1 = 1 KB
    __shared__ __align__(16) float fl[CIN];
    __shared__ float bfl[COUT];

    const int blk = blockIdx.x;          // 1024
    const int xcd = blk & 7;
    const int idx = blk >> 3;            // 0..127
    const int b   = (xcd << 5) | (idx & 31);
    const int z   = idx >> 5;            // 0..3
    const int t   = threadIdx.x;

    // ---- cooperative loads ----
    if (t < 192)
        reinterpret_cast<float4*>(geo)[t] =
            reinterpret_cast<const float4*>(geometry + (size_t)z * N * 3)[t];
    if (t < HID) {
        w1l[t]            = W1[t];
        w1l[HID + t]      = W1[HID + t];
        w1l[2 * HID + t]  = W1[2 * HID + t];
        w1l[3 * HID + t]  = b1[t];
    }
    if (t < CIN) fl[t] = features[((size_t)z * N + b) * CIN + t];
    __syncthreads();

    // ---- M phase: 2048 (i,hh) dots, 8/thread; hh fast across lanes so the
    //      Ml[i*64+hh] writes are conflict-free; each W2 line read exactly
    //      once per block (line-granular per-lane reads, L2-resident).
    {
        float4 f4r[8];
#pragma unroll
        for (int q = 0; q < 8; ++q) f4r[q] = *reinterpret_cast<const float4*>(&fl[q * 4]);
        const int hh = t & 63;
        const int i0 = t >> 6;           // 0..3
#pragma unroll
        for (int p = 0; p < 8; ++p) {
            const int i = i0 + 4 * p;    // 0..31
            const float4* w2r = reinterpret_cast<const float4*>(
                W2 + (size_t)hh * OC + i * CIN);
            float v = 0.f;
#pragma unroll
            for (int q = 0; q < 8; ++q) {
                const float4 w = w2r[q];
                const float4 f = f4r[q];
                v += w.x * f.x + w.y * f.y + w.z * f.z + w.w * f.w;
            }
            Ml[i * HID + hh] = v;
        }
        if (t < COUT) {
            const float4* b2r = reinterpret_cast<const float4*>(b2 + t * CIN);
            float v = 0.f;
#pragma unroll
            for (int q = 0; q < 8; ++q) {
                const float4 bb = b2r[q];
                const float4 f  = f4r[q];
                v += bb.x * f.x + bb.y * f.y + bb.z * f.z + bb.w * f.w;
            }
            bfl[t] = v;
        }
    }

    // per-thread geometry diffs for 8 a-rows (registers)
    const int a_thr = t & 31;
    const int i_thr = t >> 5;            // 0..7
    __syncthreads();

    const float gbx = geo[b * 3 + 0], gby = geo[b * 3 + 1], gbz = geo[b * 3 + 2];
    float dx[8], dy[8], dz[8];
#pragma unroll
    for (int u = 0; u < 8; ++u) {
        const int a = a_thr + 32 * u;
        dx[u] = gbx - geo[a * 3 + 0];
        dy[u] = gby - geo[a * 3 + 1];
        dz[u] = gbz - geo[a * 3 + 2];
    }

    float acc[8][4];
#pragma unroll
    for (int u = 0; u < 8; ++u)
#pragma unroll
        for (int v = 0; v < 4; ++v) acc[u][v] = bfl[i_thr * 4 + v];

    // ---- main loop: per k-chunk build H in registers, FMA against M ----
#pragma unroll
    for (int k4 = 0; k4 < 16; ++k4) {
        const float4 w1x = *reinterpret_cast<const float4*>(&w1l[k4 * 4]);
        const float4 w1y = *reinterpret_cast<const float4*>(&w1l[HID + k4 * 4]);
        const float4 w1z = *reinterpret_cast<const float4*>(&w1l[2 * HID + k4 * 4]);
        const float4 b1v = *reinterpret_cast<const float4*>(&w1l[3 * HID + k4 * 4]);
        float4 m[4];
#pragma unroll
        for (int v = 0; v < 4; ++v)
            m[v] = *reinterpret_cast<const float4*>(&Ml[(i_thr * 4 + v) * HID + k4 * 4]);
#pragma unroll
        for (int u = 0; u < 8; ++u) {
            float4 h;
            h.x = fmaxf(fmaf(dx[u], w1x.x, fmaf(dy[u], w1y.x, fmaf(dz[u], w1z.x, b1v.x))), 0.f);
            h.y = fmaxf(fmaf(dx[u], w1x.y, fmaf(dy[u], w1y.y, fmaf(dz[u], w1z.y, b1v.y))), 0.f);
            h.z = fmaxf(fmaf(dx[u], w1x.z, fmaf(dy[u], w1y.z, fmaf(dz[u], w1z.z, b1v.z))), 0.f);
            h.w = fmaxf(fmaf(dx[u], w1x.w, fmaf(dy[u], w1y.w, fmaf(dz[u], w1z.w, b1v.w))), 0.f);
#pragma unroll
            for (int v = 0; v < 4; ++v)
                acc[u][v] += h.x * m[v].x + h.y * m[v].y + h.z * m[v].z + h.w * m[v].w;
        }
    }

    // ---- epilogue: transpose through LDS in two 128-a halves, coalesced stores
    const size_t out_zb = ((size_t)z * N) * N + b;
#pragma unroll
    for (int half = 0; half < 2; ++half) {
        __syncthreads();   // protect stage reuse
#pragma unroll
        for (int u = 0; u < 4; ++u) {
            const int uu = half * 4 + u;
            float4 o;
            o.x = acc[uu][0]; o.y = acc[uu][1]; o.z = acc[uu][2]; o.w = acc[uu][3];
            *reinterpret_cast<float4*>(&stage[(a_thr + 32 * u) * 36 + i_thr * 4]) = o;
        }
        __syncthreads();
#pragma unroll
        for (int r = 0; r < 4; ++r) {
            const int c     = r * 256 + t;      // 0..1023
            const int a_loc = c >> 3;           // 0..127
            const int i4    = c & 7;
            const int a     = half * 128 + a_loc;
            const float4 val = *reinterpret_cast<const float4*>(&stage[a_loc * 36 + i4 * 4]);
            *reinterpret_cast<float4*>(
                &out[(out_zb + (size_t)a * N) * COUT + i4 * 4]) = val;
        }
    }
}

extern "C" void kernel_launch(void* const* d_in, const int* in_sizes, int n_in,
                              void* d_out, int out_size, void* d_ws, size_t ws_size,
                              hipStream_t stream) {
    const float* features = (const float*)d_in[0];
    const float* geometry = (const float*)d_in[1];
    const float* W1 = (const float*)d_in[2];
    const float* b1 = (const float*)d_in[3];
    const float* W2 = (const float*)d_in[4];
    const float* b2 = (const float*)d_in[5];
    float* out = (float*)d_out;

    fused_pair<<<Z * N, 256, 0, stream>>>(features, geometry, W1, b1, W2, b2, out);
}